// Round 8
// baseline (440.399 us; speedup 1.0000x reference)
//
#include <hip/hip_runtime.h>

#define NA 250000
#define NB 500000
#define NG 50000
#define DD 64
#define EA_N 1000000
#define EG_N 500000
#define FTC 320           // 5*64
#define CAP 16            // bucket slots per (bond, etype)

#define EDGE4_BLKS (((EA_N + EG_N) / 4 + 255) / 256)   // 1465
#define BOND_BLKS (NB / 16)     // 31250 (16 bonds/block, 16 lanes/bond)
#define MEGA_GRID 36864         // every 32nd block is a copy block -> 1152 copies
#define COPYA_BLKS 1024
#define COPYG_BLKS 128

// workspace layout (ints)
#define WS_CNT      0           // 2*NB
#define WS_REDO_CNT 1000000     // 1 (+15 pad)
#define WS_REDO     1000016     // 1,000,000
#define WS_SLOTS    2000016     // 2*NB*CAP = 16,000,000
#define WS_NEED_B   ((size_t)(2000016 + 2 * NB * CAP) * 4)   // 72,000,064 B

// native clang vector types — required by __builtin_nontemporal_*
typedef float vf4 __attribute__((ext_vector_type(4)));
typedef int   vi4 __attribute__((ext_vector_type(4)));

// ---------------- helpers ----------------

__device__ __forceinline__ float4 f4add(float4 a, float4 b) {
    return make_float4(a.x + b.x, a.y + b.y, a.z + b.z, a.w + b.w);
}
__device__ __forceinline__ float4 f4max(float4 a, float4 b) {
    return make_float4(fmaxf(a.x, b.x), fmaxf(a.y, b.y),
                       fmaxf(a.z, b.z), fmaxf(a.w, b.w));
}
__device__ __forceinline__ float4 f4scale(float4 a, float s) {
    return make_float4(a.x * s, a.y * s, a.z * s, a.w * s);
}
__device__ __forceinline__ float4 ntload4(const float4* p) {
    vf4 v = __builtin_nontemporal_load((const vf4*)p);
    return make_float4(v.x, v.y, v.z, v.w);
}
__device__ __forceinline__ void ntstore4(float4 a, float4* p) {
    vf4 v = {a.x, a.y, a.z, a.w};
    __builtin_nontemporal_store(v, (vf4*)p);
}
__device__ __forceinline__ vi4 ntload_i4(const int* p) {
    return __builtin_nontemporal_load((const vi4*)p);
}

// ================= main path: bucketed one-pass build =================

__global__ __launch_bounds__(256) void bucket_fill_kernel(
    const int* __restrict__ a2b_src, const int* __restrict__ a2b_dst,
    const int* __restrict__ g2b_src, const int* __restrict__ g2b_dst,
    int* __restrict__ cnt, int* __restrict__ slots,
    int* __restrict__ redo, int* __restrict__ redo_cnt) {
    int i = blockIdx.x * blockDim.x + threadIdx.x;
    int stride = gridDim.x * blockDim.x;
    const int totalA = EA_N / 4;
    const int total = (EA_N + EG_N) / 4;
    for (; i < total; i += stride) {
        vi4 d, s;
        int base, et;
        if (i < totalA) {
            d = ntload_i4(a2b_dst + 4 * i);
            s = ntload_i4(a2b_src + 4 * i);
            base = 0; et = 0;
        } else {
            d = ntload_i4(g2b_dst + 4 * (i - totalA));
            s = ntload_i4(g2b_src + 4 * (i - totalA));
            base = NB; et = 1;
        }
#define PUT(DX, SX)                                                        \
        {                                                                  \
            int seg = base + (DX);                                         \
            int pos = atomicAdd(&cnt[seg], 1);                             \
            if (pos < CAP) slots[(size_t)seg * CAP + pos] = (SX);          \
            else if (pos == CAP) {                                         \
                int r = atomicAdd(redo_cnt, 1);                            \
                redo[r] = (DX) | (et << 31);                               \
            }                                                              \
        }
        PUT(d.x, s.x) PUT(d.y, s.y) PUT(d.z, s.z) PUT(d.w, s.w)
#undef PUT
    }
}

// blocks with (bid&31)==31 are pass-through copy blocks (interleaved through
// the dispatch so copy BW backfills gather latency); the rest do bonds:
// 16 bonds/block, 16 lanes (float4 of the row) per bond.
__global__ __launch_bounds__(256) void bond_copy_kernel(
    const float4* __restrict__ bond4, const float4* __restrict__ atom4,
    const float4* __restrict__ glob4, const int* __restrict__ cnt,
    const int* __restrict__ slots, float4* __restrict__ ft4,
    float4* __restrict__ out_atom4, float4* __restrict__ out_glob4) {
    int bid = blockIdx.x;

    if ((bid & 31) == 31) {               // copy role
        int c = bid >> 5;                 // 0..1151
        if (c < COPYA_BLKS) {
            long long n4 = (long long)NA * DD / 4;
            long long i = (long long)c * 256 + threadIdx.x;
            long long stride = (long long)COPYA_BLKS * 256;
            for (; i < n4; i += stride) {
                float4 v = ntload4(&atom4[i]);
                ntstore4(v, &out_atom4[i]);
            }
        } else {
            long long n4 = (long long)NG * DD / 4;
            long long i = (long long)(c - COPYA_BLKS) * 256 + threadIdx.x;
            long long stride = (long long)COPYG_BLKS * 256;
            for (; i < n4; i += stride) {
                float4 v = ntload4(&glob4[i]);
                ntstore4(v, &out_glob4[i]);
            }
        }
        return;
    }

    int bond_blk = bid - (bid >> 5);      // # of non-copy blocks before bid
    if (bond_blk >= BOND_BLKS) return;

    long long b = (long long)bond_blk * 16 + (threadIdx.x >> 4);
    int q = threadIdx.x & 15;
    int gbase = threadIdx.x & 48;

    // level 0: everything independent issues together
    int da = cnt[b];
    int dg = cnt[NB + b];
    int ia = slots[b * CAP + q];          // q < 16 == CAP
    int ig = slots[(NB + b) * CAP + q];
    float4 bv = ntload4(&bond4[b * 16 + q]);

    int na = min(da, CAP);
    int ng = min(dg, CAP);
    int nmx = max(na, ng);

    float4 sa = make_float4(0.f, 0.f, 0.f, 0.f), sg = sa;
    float4 xa = make_float4(-INFINITY, -INFINITY, -INFINITY, -INFINITY), xg = xa;

    // gathers: 4-wide predicated unroll, atom+glob interleaved (<=8 in flight)
    for (int j0 = 0; j0 < nmx; j0 += 4) {
        float4 va0, va1, va2, va3, vg0, vg1, vg2, vg3;
        bool a0 = j0 + 0 < na, a1 = j0 + 1 < na, a2 = j0 + 2 < na, a3 = j0 + 3 < na;
        bool g0 = j0 + 0 < ng, g1 = j0 + 1 < ng, g2 = j0 + 2 < ng, g3 = j0 + 3 < ng;
        if (a0) va0 = atom4[(long long)__shfl(ia, gbase + j0 + 0, 64) * 16 + q];
        if (g0) vg0 = glob4[(long long)__shfl(ig, gbase + j0 + 0, 64) * 16 + q];
        if (a1) va1 = atom4[(long long)__shfl(ia, gbase + j0 + 1, 64) * 16 + q];
        if (g1) vg1 = glob4[(long long)__shfl(ig, gbase + j0 + 1, 64) * 16 + q];
        if (a2) va2 = atom4[(long long)__shfl(ia, gbase + j0 + 2, 64) * 16 + q];
        if (g2) vg2 = glob4[(long long)__shfl(ig, gbase + j0 + 2, 64) * 16 + q];
        if (a3) va3 = atom4[(long long)__shfl(ia, gbase + j0 + 3, 64) * 16 + q];
        if (g3) vg3 = glob4[(long long)__shfl(ig, gbase + j0 + 3, 64) * 16 + q];
        if (a0) { sa = f4add(sa, va0); xa = f4max(xa, va0); }
        if (a1) { sa = f4add(sa, va1); xa = f4max(xa, va1); }
        if (a2) { sa = f4add(sa, va2); xa = f4max(xa, va2); }
        if (a3) { sa = f4add(sa, va3); xa = f4max(xa, va3); }
        if (g0) { sg = f4add(sg, vg0); xg = f4max(xg, vg0); }
        if (g1) { sg = f4add(sg, vg1); xg = f4max(xg, vg1); }
        if (g2) { sg = f4add(sg, vg2); xg = f4max(xg, vg2); }
        if (g3) { sg = f4add(sg, vg3); xg = f4max(xg, vg3); }
    }

    float4 ma = f4scale(sa, da ? 1.f / (float)da : 0.f);
    float4 mg = f4scale(sg, dg ? 1.f / (float)dg : 0.f);
    if (!da) xa = make_float4(0.f, 0.f, 0.f, 0.f);
    if (!dg) xg = make_float4(0.f, 0.f, 0.f, 0.f);

    float4* row = ft4 + b * 80;
    ntstore4(bv, &row[q]);
    if (da <= CAP) {                      // else redo kernel writes these
        ntstore4(ma, &row[16 + q]);
        ntstore4(xa, &row[32 + q]);
    }
    if (dg <= CAP) {
        ntstore4(mg, &row[48 + q]);
        ntstore4(xg, &row[64 + q]);
    }
}

// Correctness fallback for deg > CAP bonds (statistically never runs):
// one wave per redo entry rescans the full edge list.
__global__ __launch_bounds__(256) void redo_kernel(
    const int* __restrict__ redo, const int* __restrict__ redo_cnt,
    const int* __restrict__ a2b_src, const int* __restrict__ a2b_dst,
    const int* __restrict__ g2b_src, const int* __restrict__ g2b_dst,
    const float* __restrict__ atom, const float* __restrict__ glob,
    float* __restrict__ ft) {
    int n = *redo_cnt;
    int wid = (int)((blockIdx.x * blockDim.x + threadIdx.x) >> 6);
    int lane = threadIdx.x & 63;
    int nw = (gridDim.x * blockDim.x) >> 6;
    for (int r = wid; r < n; r += nw) {
        int entry = redo[r];
        int et = (entry >> 31) & 1;
        int b = entry & 0x7fffffff;
        const int* dst = et ? g2b_dst : a2b_dst;
        const int* src = et ? g2b_src : a2b_src;
        const float* sft = et ? glob : atom;
        int E = et ? EG_N : EA_N;
        float sum = 0.f, mx = -INFINITY;
        int c = 0;
        for (int e = 0; e < E; ++e) {
            if (dst[e] == b) {
                float v = sft[(long long)src[e] * DD + lane];
                sum += v; mx = fmaxf(mx, v); ++c;
            }
        }
        float mean = c ? sum / (float)c : 0.f;
        if (!c) mx = 0.f;
        float* row = ft + (long long)b * FTC + (et ? 192 : 64);
        row[lane] = mean;
        row[64 + lane] = mx;
    }
}

// ================= fallback path (small ws): direct atomic scatter =================

__device__ __forceinline__ unsigned float_to_key(float f) {
    unsigned u = __float_as_uint(f);
    return (u & 0x80000000u) ? ~u : (u | 0x80000000u);
}
__device__ __forceinline__ float key_to_float(unsigned k) {
    unsigned u = (k & 0x80000000u) ? (k & 0x7FFFFFFFu) : ~k;
    return __uint_as_float(u);
}

__global__ void fb_copy_kernel(const float4* __restrict__ src,
                               float4* __restrict__ dst, long long n4) {
    long long i = (long long)blockIdx.x * blockDim.x + threadIdx.x;
    long long stride = (long long)gridDim.x * blockDim.x;
    for (; i < n4; i += stride) dst[i] = src[i];
}

__global__ void fb_init_ft_kernel(const float4* __restrict__ bond,
                                  float4* __restrict__ ft) {
    const long long n4 = (long long)NB * 80;
    long long i = (long long)blockIdx.x * blockDim.x + threadIdx.x;
    long long stride = (long long)gridDim.x * blockDim.x;
    for (; i < n4; i += stride) {
        long long b = i / 80;
        int c4 = (int)(i - b * 80);
        float4 v = make_float4(0.f, 0.f, 0.f, 0.f);
        if (c4 < 16) v = bond[b * 16 + c4];
        ft[i] = v;
    }
}

__global__ void fb_scatter_kernel(const float* __restrict__ src_ft,
                                  const int* __restrict__ src_idx,
                                  const int* __restrict__ dst_idx,
                                  int n_edges, float* __restrict__ ft,
                                  int sum_col, int max_col,
                                  int* __restrict__ cnt) {
    long long total = (long long)n_edges * 64;
    long long i = (long long)blockIdx.x * blockDim.x + threadIdx.x;
    long long stride = (long long)gridDim.x * blockDim.x;
    for (; i < total; i += stride) {
        int e = (int)(i >> 6);
        int d = (int)(i & 63);
        int s = src_idx[e];
        int b = dst_idx[e];
        float v = src_ft[(long long)s * DD + d];
        atomicAdd(&ft[(long long)b * FTC + sum_col + d], v);
        atomicMax((unsigned*)&ft[(long long)b * FTC + max_col + d], float_to_key(v));
        if (d == 0) atomicAdd(&cnt[b], 1);
    }
}

__global__ void fb_finalize_kernel(float* __restrict__ ft,
                                   const int* __restrict__ cnt_a,
                                   const int* __restrict__ cnt_g) {
    long long total = (long long)NB * 64;
    long long i = (long long)blockIdx.x * blockDim.x + threadIdx.x;
    long long stride = (long long)gridDim.x * blockDim.x;
    for (; i < total; i += stride) {
        long long b = i >> 6;
        int d = (int)(i & 63);
        float* row = ft + b * FTC;
        int ca = cnt_a[b];
        row[64 + d] = row[64 + d] / fmaxf((float)ca, 1.0f);
        unsigned ka = __float_as_uint(row[128 + d]);
        row[128 + d] = (ca > 0) ? key_to_float(ka) : 0.0f;
        int cg = cnt_g[b];
        row[192 + d] = row[192 + d] / fmaxf((float)cg, 1.0f);
        unsigned kg = __float_as_uint(row[256 + d]);
        row[256 + d] = (cg > 0) ? key_to_float(kg) : 0.0f;
    }
}

// ---------------- launch ----------------

extern "C" void kernel_launch(void* const* d_in, const int* in_sizes, int n_in,
                              void* d_out, int out_size, void* d_ws, size_t ws_size,
                              hipStream_t stream) {
    const float* atom_ft   = (const float*)d_in[0];
    const float* bond_ft   = (const float*)d_in[1];
    const float* global_ft = (const float*)d_in[2];
    const int* a2b_src = (const int*)d_in[3];
    const int* a2b_dst = (const int*)d_in[4];
    const int* g2b_src = (const int*)d_in[5];
    const int* g2b_dst = (const int*)d_in[6];

    float* out = (float*)d_out;
    float* out_atom = out;                            // [NA,64]
    float* out_ft   = out + (long long)NA * DD;       // [NB,320]
    float* out_glob = out_ft + (long long)NB * FTC;   // [NG,64]

    int* ws = (int*)d_ws;
    const int BLK = 256;

    if (ws_size >= WS_NEED_B) {
        int* cnt      = ws + WS_CNT;
        int* redo_cnt = ws + WS_REDO_CNT;
        int* redo     = ws + WS_REDO;
        int* slots    = ws + WS_SLOTS;

        // zero counts + redo counter in one memset
        (void)hipMemsetAsync(cnt, 0, (size_t)(WS_REDO_CNT + 16 - WS_CNT) * 4, stream);

        bucket_fill_kernel<<<EDGE4_BLKS, BLK, 0, stream>>>(
            a2b_src, a2b_dst, g2b_src, g2b_dst, cnt, slots, redo, redo_cnt);

        bond_copy_kernel<<<MEGA_GRID, BLK, 0, stream>>>(
            (const float4*)bond_ft, (const float4*)atom_ft,
            (const float4*)global_ft, cnt, slots, (float4*)out_ft,
            (float4*)out_atom, (float4*)out_glob);

        redo_kernel<<<64, BLK, 0, stream>>>(
            redo, redo_cnt, a2b_src, a2b_dst, g2b_src, g2b_dst,
            atom_ft, global_ft, out_ft);
    } else {
        // compact known-correct fallback (direct atomic scatter)
        int* cnt_a = ws;
        int* cnt_g = ws + NB;
        (void)hipMemsetAsync(ws, 0, 2 * (size_t)NB * sizeof(int), stream);
        fb_copy_kernel<<<4096, BLK, 0, stream>>>(
            (const float4*)atom_ft, (float4*)out_atom, (long long)NA * DD / 4);
        fb_copy_kernel<<<2048, BLK, 0, stream>>>(
            (const float4*)global_ft, (float4*)out_glob, (long long)NG * DD / 4);
        fb_init_ft_kernel<<<8192, BLK, 0, stream>>>(
            (const float4*)bond_ft, (float4*)out_ft);
        fb_scatter_kernel<<<8192, BLK, 0, stream>>>(
            atom_ft, a2b_src, a2b_dst, EA_N, out_ft, 64, 128, cnt_a);
        fb_scatter_kernel<<<8192, BLK, 0, stream>>>(
            global_ft, g2b_src, g2b_dst, EG_N, out_ft, 192, 256, cnt_g);
        fb_finalize_kernel<<<8192, BLK, 0, stream>>>(out_ft, cnt_a, cnt_g);
    }
}